// Round 5
// baseline (415.745 us; speedup 1.0000x reference)
//
#include <hip/hip_runtime.h>
#include <hip/hip_bf16.h>
#include <math.h>

#define TPB 256

typedef __attribute__((ext_vector_type(8))) short bfrag8;
typedef __attribute__((ext_vector_type(4))) float f32x4;
typedef __attribute__((ext_vector_type(2))) float f32x2;

static __device__ __forceinline__ f32x2 unpk2(unsigned int u) {
  union { unsigned int i; float f; } lo, hi;
  lo.i = u << 16;
  hi.i = u & 0xffff0000u;
  f32x2 r; r.x = lo.f; r.y = hi.f; return r;
}
static __device__ __forceinline__ unsigned short f2bf(float f) {
  union { float f; unsigned int i; } c; c.f = f;
  unsigned int lsb = (c.i >> 16) & 1u;
  return (unsigned short)((c.i + 0x7fffu + lsb) >> 16);
}

// DPP row-rotate ring reduction: every lane of each 16-lane row gets the row sum.
#define DPP_ROR(v, C) __int_as_float(__builtin_amdgcn_update_dpp( \
    __float_as_int(v), __float_as_int(v), (C), 0xf, 0xf, false))
static __device__ __forceinline__ float red16(float p) {
  p += DPP_ROR(p, 0x121);  // row_ror:1
  p += DPP_ROR(p, 0x122);  // row_ror:2
  p += DPP_ROR(p, 0x124);  // row_ror:4
  p += DPP_ROR(p, 0x128);  // row_ror:8
  return p;
}

// ---------------- CSR build ----------------
__global__ void k_deg(const int* __restrict__ ei, int E, int ET, int* __restrict__ deg) {
  int e = blockIdx.x * blockDim.x + threadIdx.x;
  if (e >= ET) return;
  int dst = (e < E) ? ei[E + e] : (e - E);
  atomicAdd(&deg[dst], 1);
}

__global__ void k_scan1(const int* __restrict__ deg, int N, int* __restrict__ bsum) {
  __shared__ int sm[TPB];
  int i = blockIdx.x * TPB + threadIdx.x;
  sm[threadIdx.x] = (i < N) ? deg[i] : 0;
  __syncthreads();
  for (int d = TPB / 2; d > 0; d >>= 1) {
    if (threadIdx.x < d) sm[threadIdx.x] += sm[threadIdx.x + d];
    __syncthreads();
  }
  if (threadIdx.x == 0) bsum[blockIdx.x] = sm[0];
}

// requires SB <= TPB (N <= 65536)
__global__ void k_scan3(const int* __restrict__ deg, const int* __restrict__ bsum,
                        int SB, int N, int* __restrict__ rowoff, int* __restrict__ cursor) {
  __shared__ int sm[TPB];
  int pv = (threadIdx.x < blockIdx.x) ? bsum[threadIdx.x] : 0;
  sm[threadIdx.x] = pv;
  __syncthreads();
  for (int dd = TPB / 2; dd > 0; dd >>= 1) {
    if (threadIdx.x < dd) sm[threadIdx.x] += sm[threadIdx.x + dd];
    __syncthreads();
  }
  int base = sm[0];
  __syncthreads();
  int i = blockIdx.x * TPB + threadIdx.x;
  int v = (i < N) ? deg[i] : 0;
  sm[threadIdx.x] = v;
  __syncthreads();
  for (int dd = 1; dd < TPB; dd <<= 1) {
    int t = (threadIdx.x >= dd) ? sm[threadIdx.x - dd] : 0;
    __syncthreads();
    sm[threadIdx.x] += t;
    __syncthreads();
  }
  if (i < N) {
    int off = base + sm[threadIdx.x] - v;  // exclusive
    rowoff[i] = off;
    cursor[i] = off;
  }
  if (blockIdx.x == SB - 1 && threadIdx.x == TPB - 1) rowoff[N] = base + sm[TPB - 1];
}

__global__ void k_fill(const int* __restrict__ ei, int E, int ET,
                       int* __restrict__ cursor, int* __restrict__ csrc) {
  int e = blockIdx.x * blockDim.x + threadIdx.x;
  if (e >= ET) return;
  int src, dst;
  if (e < E) { src = ei[e]; dst = ei[E + e]; } else { src = dst = e - E; }
  int pos = atomicAdd(&cursor[dst], 1);
  csrc[pos] = src;
}

// ---------------- prep: f32 -> bf16 conversions (x, transposed W's) ----------------
__global__ void k_prep1(const float* __restrict__ x,
                        const float* __restrict__ Wl1, const float* __restrict__ Wr1,
                        const float* __restrict__ Wl2, const float* __restrict__ Wr2,
                        unsigned short* __restrict__ xb,
                        unsigned short* __restrict__ wt1l, unsigned short* __restrict__ wt1r,
                        unsigned short* __restrict__ wt2l, unsigned short* __restrict__ wt2r,
                        int nx4) {
  int i = blockIdx.x * blockDim.x + threadIdx.x;
  int stride = gridDim.x * blockDim.x;
  int wtot = nx4 + 65536 + 8192;
  for (; i < wtot; i += stride) {
    if (i < nx4) {
      float4 v = *(const float4*)(x + (size_t)i * 4);
      ushort4 o; o.x = f2bf(v.x); o.y = f2bf(v.y); o.z = f2bf(v.z); o.w = f2bf(v.w);
      *(ushort4*)(xb + (size_t)i * 4) = o;
    } else if (i < nx4 + 32768) {
      int j = i - nx4; int c = j >> 7, k = j & 127;
      wt1l[j] = f2bf(Wl1[(size_t)k * 256 + c]);
    } else if (i < nx4 + 65536) {
      int j = i - nx4 - 32768; int c = j >> 7, k = j & 127;
      wt1r[j] = f2bf(Wr1[(size_t)k * 256 + c]);
    } else if (i < nx4 + 65536 + 4096) {
      int j = i - nx4 - 65536; int c = j >> 6, k = j & 63;
      wt2l[j] = f2bf(Wl2[(size_t)k * 64 + c]);
    } else {
      int j = i - nx4 - 69632; int c = j >> 6, k = j & 63;
      wt2r[j] = f2bf(Wr2[(size_t)k * 64 + c]);
    }
  }
}

// prep2: BN affine + relu + bf16 (layer-2 GEMM input)
__global__ void k_prep2(const float* __restrict__ in, const float* __restrict__ ab,
                        unsigned short* __restrict__ o, int n4) {
  int i = blockIdx.x * blockDim.x + threadIdx.x;
  if (i >= n4) return;
  float4 v = *(const float4*)(in + (size_t)i * 4);
  int c0 = (i & 15) * 4;
  ushort4 u;
  u.x = f2bf(fmaxf(v.x * ab[c0 + 0] + ab[64 + c0 + 0], 0.f));
  u.y = f2bf(fmaxf(v.y * ab[c0 + 1] + ab[64 + c0 + 1], 0.f));
  u.z = f2bf(fmaxf(v.z * ab[c0 + 2] + ab[64 + c0 + 2], 0.f));
  u.w = f2bf(fmaxf(v.w * ab[c0 + 3] + ab[64 + c0 + 3], 0.f));
  *(ushort4*)(o + (size_t)i * 4) = u;
}

// ---------------- MFMA GEMM (bf16 in): out{0,1} = Ab @ Wt{0,1}^T + b{0,1} ----------------
__global__ void k_gemm_mfma(const unsigned short* __restrict__ Ab,
                            const unsigned short* __restrict__ Wt0, const float* __restrict__ b0,
                            const unsigned short* __restrict__ Wt1, const float* __restrict__ b1,
                            unsigned short* __restrict__ out0, unsigned short* __restrict__ out1,
                            int M, int K, int Nc) {
  extern __shared__ short lds[];
  short* As = lds;
  short* Bls = lds + 64 * K;
  short* Brs = lds + 128 * K;
  const int r0 = blockIdx.x * 64, n0 = blockIdx.y * 64;
  const int tid = threadIdx.x;
  const int Kb = K * 2;
  const int cpr = K >> 3;          // 16B chunks per row
  const int chunks = 64 * cpr;
  for (int idx = tid; idx < chunks; idx += TPB) {
    int row = idx / cpr, k8 = (idx - row * cpr) * 8;
    int kb = (k8 * 2) ^ ((row & 7) << 4);
    int gr = r0 + row;
    uint4 av = make_uint4(0, 0, 0, 0);
    if (gr < M) av = *(const uint4*)(Ab + (size_t)gr * K + k8);
    *(uint4*)((char*)As + row * Kb + kb) = av;
    uint4 w0 = *(const uint4*)(Wt0 + (size_t)(n0 + row) * K + k8);
    *(uint4*)((char*)Bls + row * Kb + kb) = w0;
    uint4 w1 = *(const uint4*)(Wt1 + (size_t)(n0 + row) * K + k8);
    *(uint4*)((char*)Brs + row * Kb + kb) = w1;
  }
  __syncthreads();

  const int w = tid >> 6, lane = tid & 63;
  const int arow = w * 16 + (lane & 15);
  const int l16 = (lane >> 4) << 3;
  f32x4 accL[4], accR[4];
#pragma unroll
  for (int i = 0; i < 4; ++i) { accL[i] = (f32x4)0.f; accR[i] = (f32x4)0.f; }
  for (int k0 = 0; k0 < K; k0 += 32) {
    int kb = (k0 + l16) * 2;
    bfrag8 af = *(bfrag8*)((char*)As + arow * Kb + (kb ^ ((arow & 7) << 4)));
#pragma unroll
    for (int cf = 0; cf < 4; ++cf) {
      int col = cf * 16 + (lane & 15);
      int cb = col * Kb + (kb ^ ((col & 7) << 4));
      bfrag8 bl = *(bfrag8*)((char*)Bls + cb);
      accL[cf] = __builtin_amdgcn_mfma_f32_16x16x32_bf16(af, bl, accL[cf], 0, 0, 0);
      bfrag8 br = *(bfrag8*)((char*)Brs + cb);
      accR[cf] = __builtin_amdgcn_mfma_f32_16x16x32_bf16(af, br, accR[cf], 0, 0, 0);
    }
  }
  const int rbase = r0 + w * 16 + ((lane >> 4) << 2);
  const int cbase = n0 + (lane & 15);
#pragma unroll
  for (int cf = 0; cf < 4; ++cf) {
    int gcol = cbase + cf * 16;
    float bb0 = b0[gcol], bb1 = b1[gcol];
#pragma unroll
    for (int r = 0; r < 4; ++r) {
      int grow = rbase + r;
      if (grow < M) {
        out0[(size_t)grow * Nc + gcol] = f2bf(accL[cf][r] + bb0);
        out1[(size_t)grow * Nc + gcol] = f2bf(accR[cf][r] + bb1);
      }
    }
  }
}

// ---------------- GATv2 layer 1: H=4, C=64; one node/wave ----------------
// 32-bit saddr offsets, dwordx4 csrc loads, DPP reductions, 8-edge main loop.
__global__ __launch_bounds__(TPB) void k_gat1(
    const unsigned short* __restrict__ xl, const unsigned short* __restrict__ xr,
    const int* __restrict__ rowoff, const int* __restrict__ csrc,
    const float* __restrict__ att, const float* __restrict__ bias,
    float* __restrict__ out, int N) {
  int node = (blockIdx.x * blockDim.x + threadIdx.x) >> 6;
  int lane = threadIdx.x & 63;
  if (node >= N) return;
  int l4 = lane * 4;
  float4 atv = *(const float4*)(att + l4);
  f32x2 at01; at01.x = atv.x; at01.y = atv.y;
  f32x2 at23; at23.x = atv.z; at23.y = atv.w;
  float4 bb = *(const float4*)(bias + l4);
  uint2 rv = *(const uint2*)(xr + ((node << 8) + l4));
  f32x2 xr01 = unpk2(rv.x), xr23 = unpk2(rv.y);
  int beg = rowoff[node], end = rowoff[node + 1];
  float sA = 0.f, sB = 0.f;
  f32x2 acA01 = {0.f, 0.f}, acA23 = {0.f, 0.f};
  f32x2 acB01 = {0.f, 0.f}, acB23 = {0.f, 0.f};
  int k = beg;
  for (; k + 8 <= end; k += 8) {
    int4 qa = *(const int4*)(csrc + k);
    int4 qb = *(const int4*)(csrc + k + 4);
    uint2 vv[8];
    vv[0] = *(const uint2*)(xl + ((qa.x << 8) + l4));
    vv[1] = *(const uint2*)(xl + ((qa.y << 8) + l4));
    vv[2] = *(const uint2*)(xl + ((qa.z << 8) + l4));
    vv[3] = *(const uint2*)(xl + ((qa.w << 8) + l4));
    vv[4] = *(const uint2*)(xl + ((qb.x << 8) + l4));
    vv[5] = *(const uint2*)(xl + ((qb.y << 8) + l4));
    vv[6] = *(const uint2*)(xl + ((qb.z << 8) + l4));
    vv[7] = *(const uint2*)(xl + ((qb.w << 8) + l4));
    // quad A
    {
      f32x2 x01[4], x23[4]; float ps[4];
#pragma unroll
      for (int u = 0; u < 4; ++u) {
        x01[u] = unpk2(vv[u].x); x23[u] = unpk2(vv[u].y);
        f32x2 t01 = x01[u] + xr01, t23 = x23[u] + xr23;
        f32x2 m01 = t01 * 0.2f, m23 = t23 * 0.2f;
        f32x2 l01, l23;
        l01.x = fmaxf(t01.x, m01.x); l01.y = fmaxf(t01.y, m01.y);
        l23.x = fmaxf(t23.x, m23.x); l23.y = fmaxf(t23.y, m23.y);
        f32x2 pf = at01 * l01 + at23 * l23;
        ps[u] = pf.x + pf.y;
      }
#pragma unroll
      for (int u = 0; u < 4; ++u) ps[u] = red16(ps[u]);
#pragma unroll
      for (int u = 0; u < 4; ++u) {
        float wv = __expf(ps[u]);
        sA += wv;
        acA01 += x01[u] * wv;
        acA23 += x23[u] * wv;
      }
    }
    // quad B
    {
      f32x2 x01[4], x23[4]; float ps[4];
#pragma unroll
      for (int u = 0; u < 4; ++u) {
        x01[u] = unpk2(vv[4 + u].x); x23[u] = unpk2(vv[4 + u].y);
        f32x2 t01 = x01[u] + xr01, t23 = x23[u] + xr23;
        f32x2 m01 = t01 * 0.2f, m23 = t23 * 0.2f;
        f32x2 l01, l23;
        l01.x = fmaxf(t01.x, m01.x); l01.y = fmaxf(t01.y, m01.y);
        l23.x = fmaxf(t23.x, m23.x); l23.y = fmaxf(t23.y, m23.y);
        f32x2 pf = at01 * l01 + at23 * l23;
        ps[u] = pf.x + pf.y;
      }
#pragma unroll
      for (int u = 0; u < 4; ++u) ps[u] = red16(ps[u]);
#pragma unroll
      for (int u = 0; u < 4; ++u) {
        float wv = __expf(ps[u]);
        sB += wv;
        acB01 += x01[u] * wv;
        acB23 += x23[u] * wv;
      }
    }
  }
  for (; k < end; k += 4) {  // predicated quad tail
    int srcs[4]; bool okv[4];
#pragma unroll
    for (int u = 0; u < 4; ++u) {
      okv[u] = (k + u) < end;
      srcs[u] = okv[u] ? csrc[k + u] : csrc[k];
    }
    uint2 vv[4];
#pragma unroll
    for (int u = 0; u < 4; ++u) vv[u] = *(const uint2*)(xl + ((srcs[u] << 8) + l4));
    f32x2 x01[4], x23[4]; float ps[4];
#pragma unroll
    for (int u = 0; u < 4; ++u) {
      x01[u] = unpk2(vv[u].x); x23[u] = unpk2(vv[u].y);
      f32x2 t01 = x01[u] + xr01, t23 = x23[u] + xr23;
      f32x2 m01 = t01 * 0.2f, m23 = t23 * 0.2f;
      f32x2 l01, l23;
      l01.x = fmaxf(t01.x, m01.x); l01.y = fmaxf(t01.y, m01.y);
      l23.x = fmaxf(t23.x, m23.x); l23.y = fmaxf(t23.y, m23.y);
      f32x2 pf = at01 * l01 + at23 * l23;
      ps[u] = pf.x + pf.y;
    }
#pragma unroll
    for (int u = 0; u < 4; ++u) ps[u] = red16(ps[u]);
#pragma unroll
    for (int u = 0; u < 4; ++u) {
      float wv = okv[u] ? __expf(ps[u]) : 0.f;
      sA += wv;
      acA01 += x01[u] * wv;
      acA23 += x23[u] * wv;
    }
  }
  float s = sA + sB;
  f32x2 ac01 = acA01 + acB01, ac23 = acA23 + acB23;
  float inv = 1.f / (s + 1e-16f);
  float a0 = ac01.x * inv, a1 = ac01.y * inv, a2 = ac23.x * inv, a3 = ac23.y * inv;
  // mean over the 4 heads
  a0 += __shfl_xor(a0, 16); a0 += __shfl_xor(a0, 32);
  a1 += __shfl_xor(a1, 16); a1 += __shfl_xor(a1, 32);
  a2 += __shfl_xor(a2, 16); a2 += __shfl_xor(a2, 32);
  a3 += __shfl_xor(a3, 16); a3 += __shfl_xor(a3, 32);
  if (lane < 16) {
    float4 o;
    o.x = a0 * 0.25f + bb.x;
    o.y = a1 * 0.25f + bb.y;
    o.z = a2 * 0.25f + bb.z;
    o.w = a3 * 0.25f + bb.w;
    *(float4*)(out + ((node << 6) + l4)) = o;
  }
}

// ---------------- GATv2 layer 2: H=1, C=64; 4 edges per wave iter, 2x unroll ----------------
__global__ __launch_bounds__(TPB) void k_gat2(
    const unsigned short* __restrict__ xl, const unsigned short* __restrict__ xr,
    const int* __restrict__ rowoff, const int* __restrict__ csrc,
    const float* __restrict__ att, const float* __restrict__ bias,
    float* __restrict__ out, int N) {
  int node = (blockIdx.x * blockDim.x + threadIdx.x) >> 6;
  int lane = threadIdx.x & 63;
  if (node >= N) return;
  int grp = lane >> 4, c4 = (lane & 15) * 4;
  float4 atv = *(const float4*)(att + c4);
  f32x2 at01; at01.x = atv.x; at01.y = atv.y;
  f32x2 at23; at23.x = atv.z; at23.y = atv.w;
  float4 bb = *(const float4*)(bias + c4);
  uint2 rv = *(const uint2*)(xr + ((node << 6) + c4));
  f32x2 xr01 = unpk2(rv.x), xr23 = unpk2(rv.y);
  int beg = rowoff[node], end = rowoff[node + 1];
  float s = 0.f;
  f32x2 ac01 = {0.f, 0.f}, ac23 = {0.f, 0.f};
  int k = beg;
  for (; k + 8 <= end; k += 8) {
    int src0 = csrc[k + grp];
    int src1 = csrc[k + 4 + grp];
    uint2 v0 = *(const uint2*)(xl + ((src0 << 6) + c4));
    uint2 v1 = *(const uint2*)(xl + ((src1 << 6) + c4));
#pragma unroll
    for (int h = 0; h < 2; ++h) {
      uint2 v = h ? v1 : v0;
      f32x2 x01 = unpk2(v.x), x23 = unpk2(v.y);
      f32x2 t01 = x01 + xr01, t23 = x23 + xr23;
      f32x2 m01 = t01 * 0.2f, m23 = t23 * 0.2f;
      f32x2 l01, l23;
      l01.x = fmaxf(t01.x, m01.x); l01.y = fmaxf(t01.y, m01.y);
      l23.x = fmaxf(t23.x, m23.x); l23.y = fmaxf(t23.y, m23.y);
      f32x2 pf = at01 * l01 + at23 * l23;
      float p = red16(pf.x + pf.y);
      float wv = __expf(p);
      s += wv;
      ac01 += x01 * wv;
      ac23 += x23 * wv;
    }
  }
  for (; k < end; k += 4) {  // predicated tail
    int kk = k + grp;
    bool ok = kk < end;
    int src = ok ? csrc[kk] : csrc[k];
    uint2 v = *(const uint2*)(xl + ((src << 6) + c4));
    f32x2 x01 = unpk2(v.x), x23 = unpk2(v.y);
    f32x2 t01 = x01 + xr01, t23 = x23 + xr23;
    f32x2 m01 = t01 * 0.2f, m23 = t23 * 0.2f;
    f32x2 l01, l23;
    l01.x = fmaxf(t01.x, m01.x); l01.y = fmaxf(t01.y, m01.y);
    l23.x = fmaxf(t23.x, m23.x); l23.y = fmaxf(t23.y, m23.y);
    f32x2 pf = at01 * l01 + at23 * l23;
    float p = red16(pf.x + pf.y);
    float wv = ok ? __expf(p) : 0.f;
    s += wv;
    ac01 += x01 * wv;
    ac23 += x23 * wv;
  }
  // sum the 4 edge-groups
  s += __shfl_xor(s, 16); s += __shfl_xor(s, 32);
  float a0 = ac01.x, a1 = ac01.y, a2 = ac23.x, a3 = ac23.y;
  a0 += __shfl_xor(a0, 16); a0 += __shfl_xor(a0, 32);
  a1 += __shfl_xor(a1, 16); a1 += __shfl_xor(a1, 32);
  a2 += __shfl_xor(a2, 16); a2 += __shfl_xor(a2, 32);
  a3 += __shfl_xor(a3, 16); a3 += __shfl_xor(a3, 32);
  if (lane < 16) {
    float inv = 1.f / (s + 1e-16f);
    float4 o;
    o.x = a0 * inv + bb.x;
    o.y = a1 * inv + bb.y;
    o.z = a2 * inv + bb.z;
    o.w = a3 * inv + bb.w;
    *(float4*)(out + ((node << 6) + c4)) = o;
  }
}

// ---------------- BatchNorm ----------------
__global__ void k_bnstat(const float* __restrict__ in, int N, float* __restrict__ part) {
  __shared__ float sm[TPB], sq[TPB];
  int col = threadIdx.x & 63;
  int rq = threadIdx.x >> 6;
  float s = 0.f, q = 0.f;
  for (int r = blockIdx.x * 4 + rq; r < N; r += gridDim.x * 4) {
    float v = in[(size_t)r * 64 + col];
    s += v; q += v * v;
  }
  sm[threadIdx.x] = s; sq[threadIdx.x] = q;
  __syncthreads();
  if (threadIdx.x < 64) {
    s = sm[threadIdx.x] + sm[threadIdx.x + 64] + sm[threadIdx.x + 128] + sm[threadIdx.x + 192];
    q = sq[threadIdx.x] + sq[threadIdx.x + 64] + sq[threadIdx.x + 128] + sq[threadIdx.x + 192];
    part[(size_t)blockIdx.x * 128 + threadIdx.x] = s;
    part[(size_t)blockIdx.x * 128 + 64 + threadIdx.x] = q;
  }
}

__global__ void k_bnfin(const float* __restrict__ part, int B, int N,
                        const float* __restrict__ g, const float* __restrict__ beta,
                        float* __restrict__ ab) {
  int c = threadIdx.x;  // 64 threads
  float s = 0.f, q = 0.f;
  for (int b = 0; b < B; ++b) {
    s += part[(size_t)b * 128 + c];
    q += part[(size_t)b * 128 + 64 + c];
  }
  float mean = s / (float)N;
  float var = q / (float)N - mean * mean;
  float a = g[c] * rsqrtf(var + 1e-5f);
  ab[c] = a;
  ab[64 + c] = beta[c] - mean * a;
}

__global__ void k_bnapply(const float* __restrict__ in, const float* __restrict__ ab,
                          float* __restrict__ out, int total4) {
  int idx = blockIdx.x * blockDim.x + threadIdx.x;
  if (idx >= total4) return;
  float4 v = *(const float4*)(in + (size_t)idx * 4);
  int c0 = (idx & 15) * 4;
  v.x = fmaxf(v.x * ab[c0 + 0] + ab[64 + c0 + 0], 0.f);
  v.y = fmaxf(v.y * ab[c0 + 1] + ab[64 + c0 + 1], 0.f);
  v.z = fmaxf(v.z * ab[c0 + 2] + ab[64 + c0 + 2], 0.f);
  v.w = fmaxf(v.w * ab[c0 + 3] + ab[64 + c0 + 3], 0.f);
  *(float4*)(out + (size_t)idx * 4) = v;
}

extern "C" void kernel_launch(void* const* d_in, const int* in_sizes, int n_in,
                              void* d_out, int out_size, void* d_ws, size_t ws_size,
                              hipStream_t stream) {
  const float* x     = (const float*)d_in[0];
  const int*   ei    = (const int*)d_in[1];
  const float* Wl1   = (const float*)d_in[2];
  const float* bl1   = (const float*)d_in[3];
  const float* Wr1   = (const float*)d_in[4];
  const float* br1   = (const float*)d_in[5];
  const float* att1  = (const float*)d_in[6];
  const float* bias1 = (const float*)d_in[7];
  const float* g1    = (const float*)d_in[8];
  const float* be1   = (const float*)d_in[9];
  const float* Wl2   = (const float*)d_in[10];
  const float* bl2   = (const float*)d_in[11];
  const float* Wr2   = (const float*)d_in[12];
  const float* br2   = (const float*)d_in[13];
  const float* att2  = (const float*)d_in[14];
  const float* bias2 = (const float*)d_in[15];
  const float* g2    = (const float*)d_in[16];
  const float* be2   = (const float*)d_in[17];
  float* out = (float*)d_out;

  const int N  = in_sizes[0] / 128;   // 50000
  const int E  = in_sizes[1] / 2;     // 800000
  const int ET = E + N;
  const int SB = (N + TPB - 1) / TPB; // 196 (<= TPB required)

  char* p = (char*)d_ws;
  auto take = [&](size_t b) { char* q = p; p += (b + 255) & ~(size_t)255; return q; };

  unsigned short* xl1 = (unsigned short*)take((size_t)N * 256 * 2);
  unsigned short* xr1 = (unsigned short*)take((size_t)N * 256 * 2);
  unsigned short* xl2 = (unsigned short*)take((size_t)N * 64 * 2);
  unsigned short* xr2 = (unsigned short*)take((size_t)N * 64 * 2);
  float* out1 = (float*)take((size_t)N * 64 * 4);
  unsigned short* xb = (unsigned short*)take((size_t)N * 128 * 2);  // reused as A2
  unsigned short* wt1l = (unsigned short*)take(256 * 128 * 2);
  unsigned short* wt1r = (unsigned short*)take(256 * 128 * 2);
  unsigned short* wt2l = (unsigned short*)take(64 * 64 * 2);
  unsigned short* wt2r = (unsigned short*)take(64 * 64 * 2);
  int* deg    = (int*)take((size_t)N * 4);
  int* rowoff = (int*)take((size_t)(N + 1) * 4);
  int* cursor = (int*)take((size_t)N * 4);
  int* csrc   = (int*)take((size_t)ET * 4 + 16);  // +16: dwordx4 tail overread slack
  int* bsum   = (int*)take((size_t)SB * 4);
  float* part = (float*)take((size_t)256 * 128 * 4);
  float* ab1  = (float*)take(128 * 4);
  float* ab2  = (float*)take(128 * 4);
  (void)ws_size; (void)n_in; (void)out_size;

  unsigned short* A2 = xb;  // layer-2 GEMM input aliases xb (xb dead after gemm1)

  int egrid = (ET + TPB - 1) / TPB;
  int ngrid = (N + 3) / 4;            // one node per wave, 4 waves/block
  int mtile = (N + 63) / 64;          // 782
  int total4 = N * 16;
  int nx4 = N * 32;                   // N*128/4
  int wtot = nx4 + 65536 + 8192;

  // CSR build
  hipMemsetAsync(deg, 0, (size_t)N * 4, stream);
  k_deg<<<egrid, TPB, 0, stream>>>(ei, E, ET, deg);
  k_scan1<<<SB, TPB, 0, stream>>>(deg, N, bsum);
  k_scan3<<<SB, TPB, 0, stream>>>(deg, bsum, SB, N, rowoff, cursor);
  k_fill<<<egrid, TPB, 0, stream>>>(ei, E, ET, cursor, csrc);

  // prep: bf16 conversions
  k_prep1<<<(wtot + TPB - 1) / TPB, TPB, 0, stream>>>(x, Wl1, Wr1, Wl2, Wr2,
                                                      xb, wt1l, wt1r, wt2l, wt2r, nx4);

  // Layer 1
  k_gemm_mfma<<<dim3(mtile, 4), TPB, 3 * 64 * 128 * 2, stream>>>(
      xb, wt1l, bl1, wt1r, br1, xl1, xr1, N, 128, 256);
  k_gat1<<<ngrid, TPB, 0, stream>>>(xl1, xr1, rowoff, csrc, att1, bias1, out1, N);
  k_bnstat<<<256, TPB, 0, stream>>>(out1, N, part);
  k_bnfin<<<1, 64, 0, stream>>>(part, 256, N, g1, be1, ab1);

  // Layer 2
  k_prep2<<<(total4 + TPB - 1) / TPB, TPB, 0, stream>>>(out1, ab1, A2, total4);
  k_gemm_mfma<<<dim3(mtile, 1), TPB, 3 * 64 * 64 * 2, stream>>>(
      A2, wt2l, bl2, wt2r, br2, xl2, xr2, N, 64, 64);
  k_gat2<<<ngrid, TPB, 0, stream>>>(xl2, xr2, rowoff, csrc, att2, bias2, out, N);
  k_bnstat<<<256, TPB, 0, stream>>>(out, N, part);
  k_bnfin<<<1, 64, 0, stream>>>(part, 256, N, g2, be2, ab2);
  k_bnapply<<<(total4 + TPB - 1) / TPB, TPB, 0, stream>>>(out, ab2, out, total4);
}